// Round 3
// baseline (276.566 us; speedup 1.0000x reference)
//
#include <hip/hip_runtime.h>
#include <hip/hip_bf16.h>

#define BB   4
#define LL   8192
#define HH   256
#define NN   64
#define NSEG 128
#define LSEG 64

// ws layout (bytes):
//       0 : lam[2*NN]      f32  (512)    per-n lambda (re,im)
//     512 : lam64[2*NN]    f32  (512)    lambda^64
//    1024 : flags[8]       i32  (32)     per-input dtype: 1=bf16, 0=fp32
//    1088 : Df[HH]         f32  (1024)
//    2112 : CBt[NN*2*HH]   f32  (131072) [n][re/im][h]
//  135168 : Abuf           bf16 (33554432) [b][hg][seg][n][re/im][64 h-lane]
// total 33,689,600 B (~32.1 MiB)
//
// DTYPE MODEL (validated against rounds 0-2): output is FP32; inputs are a
// mix (x likely bf16, params fp32) — resolved at runtime by k_sniff.

__device__ __forceinline__ float ldF(const void* p, size_t i, int isbf) {
    return isbf ? __bfloat162float(((const __hip_bfloat16*)p)[i])
                : ((const float*)p)[i];
}

// Per-input dtype sniff on the first 32 dwords (128 B).
// For each dword's LOW 16 bits classify:
//   zero      : 0x0000  (fp32 of a bf16-rounded value, or rare exact-zero bf16)
//   bf16-ish  : nonzero with exponent field in [90,140] (plausible value for
//               these normal/log distributions)
//   random    : anything else (fp32 mantissa bits)
// bf16 buffer  <=> no "random" dwords AND >=8 bf16-ish ones.
// fp32 raw     -> ~80% of dwords are "random"        -> fp32.  P(err) ~ 4e-23.
// fp32 rounded -> all low halves zero                -> fp32.
__global__ void k_sniff(const void* p0, const void* p1, const void* p2,
                        const void* p3, const void* p4, const void* p5,
                        const void* p6, const void* p7, int* flags)
{
    int t = threadIdx.x;
    if (t < 8) {
        const void* ps[8] = {p0, p1, p2, p3, p4, p5, p6, p7};
        const unsigned int* d = (const unsigned int*)ps[t];
        int nbf = 0, nrand = 0;
        for (int i = 0; i < 32; ++i) {
            unsigned int lo = d[i] & 0xFFFFu;
            unsigned int e  = (lo >> 7) & 0xFFu;
            if (lo == 0u) { /* zero: neutral */ }
            else if (e >= 90u && e <= 140u) nbf++;
            else nrand++;
        }
        flags[t] = (nrand == 0 && nbf >= 8) ? 1 : 0;
    }
}

__global__ __launch_bounds__(256) void k_setup(
    const void* nu_log, const void* theta_log,
    const void* B_re, const void* B_im,
    const void* C_re, const void* C_im,
    const void* D, const int* __restrict__ flags,
    float* lam, float* lam64, float* Df, float* CBt)
{
    int t = blockIdx.x * 256 + threadIdx.x;
    if (t < NN) {
        float nu = expf(ldF(nu_log, t, flags[1]));
        float th = expf(ldF(theta_log, t, flags[2]));
        float a  = expf(-nu);
        lam[2*t]   = a * cosf(th);
        lam[2*t+1] = a * sinf(th);
        float a64 = expf(-64.0f * nu);
        float ph  = 64.0f * th;
        lam64[2*t]   = a64 * cosf(ph);
        lam64[2*t+1] = a64 * sinf(ph);
    }
    if (t < HH) Df[t] = ldF(D, t, flags[7]);
    if (t < HH * NN) {
        int h = t >> 6, n = t & 63;
        float bre = ldF(B_re, h*NN+n, flags[3]);
        float bim = ldF(B_im, h*NN+n, flags[4]);
        float cre = ldF(C_re, h*NN+n, flags[5]);
        float cim = ldF(C_im, h*NN+n, flags[6]);
        CBt[(n*2+0)*HH + h] = cre*bre - cim*bim;
        CBt[(n*2+1)*HH + h] = cre*bim + cim*bre;
    }
}

// Phase A: segment-local weighted sums A[n] = sum_l lambda^(63-l) x_l
__global__ __launch_bounds__(256) void k_segsum(
    const void* __restrict__ x, const float* __restrict__ lam,
    const int* __restrict__ flags, __hip_bfloat16* __restrict__ Abuf)
{
    int w    = blockIdx.x * 4 + (threadIdx.x >> 6);
    int lane = threadIdx.x & 63;
    int seg  = w & (NSEG - 1);
    int hg   = (w >> 7) & 3;
    int b    = w >> 9;

    size_t xoff = (size_t)(b*LL + seg*LSEG) * HH + hg*64 + lane;
    float xv[LSEG];
    if (flags[0]) {
        const __hip_bfloat16* xp = (const __hip_bfloat16*)x + xoff;
        #pragma unroll
        for (int l = 0; l < LSEG; ++l) xv[l] = __bfloat162float(xp[(size_t)l * HH]);
    } else {
        const float* xp = (const float*)x + xoff;
        #pragma unroll
        for (int l = 0; l < LSEG; ++l) xv[l] = xp[(size_t)l * HH];
    }

    size_t abase = (((size_t)(b*4 + hg) * NSEG + seg) * NN) * 128 + lane;
    for (int n = 0; n < NN; ++n) {
        float lre = lam[2*n], lim = lam[2*n+1];
        float are = 0.f, aim = 0.f, pre = 1.f, pim = 0.f;
        #pragma unroll
        for (int i = 0; i < LSEG; ++i) {
            float xl = xv[LSEG - 1 - i];
            are = fmaf(pre, xl, are);
            aim = fmaf(pim, xl, aim);
            float t = fmaf(pre, lre, -(pim * lim));
            pim = fmaf(pre, lim, pim * lre);
            pre = t;
        }
        Abuf[abase + (size_t)n*128]      = __float2bfloat16(are);
        Abuf[abase + (size_t)n*128 + 64] = __float2bfloat16(aim);
    }
}

// Phase B: in-place scan across segments: S_end[s] = lam^64 * S_end[s-1] + A[s]
__global__ __launch_bounds__(256) void k_scan(
    const float* __restrict__ lam64, __hip_bfloat16* __restrict__ Abuf)
{
    int w    = blockIdx.x * 4 + (threadIdx.x >> 6);
    int lane = threadIdx.x & 63;
    int n    = w & 63;
    int hg   = (w >> 6) & 3;
    int b    = w >> 8;

    float lre = lam64[2*n], lim = lam64[2*n+1];
    float sre = 0.f, sim = 0.f;
    size_t base0 = (((size_t)(b*4 + hg) * NSEG) * NN + n) * 128 + lane;
    for (int s = 0; s < NSEG; ++s) {
        size_t base = base0 + (size_t)s * NN * 128;
        float are = __bfloat162float(Abuf[base]);
        float aim = __bfloat162float(Abuf[base + 64]);
        float t = fmaf(lre, sre, fmaf(-lim, sim, are));
        sim = fmaf(lre, sim, fmaf(lim, sre, aim));
        sre = t;
        Abuf[base]      = __float2bfloat16(sre);
        Abuf[base + 64] = __float2bfloat16(sim);
    }
}

// Phase C: re-run recurrence per segment seeded with S_end[seg-1], emit y (fp32)
__global__ __launch_bounds__(256) void k_out(
    const void* __restrict__ x, const float* __restrict__ lam,
    const float* __restrict__ Df, const float* __restrict__ CBt,
    const int* __restrict__ flags,
    const __hip_bfloat16* __restrict__ Abuf, float* __restrict__ y)
{
    int w    = blockIdx.x * 4 + (threadIdx.x >> 6);
    int lane = threadIdx.x & 63;
    int seg  = w & (NSEG - 1);
    int hg   = (w >> 7) & 3;
    int b    = w >> 9;
    int h    = hg*64 + lane;

    size_t xoff = (size_t)(b*LL + seg*LSEG) * HH + h;
    float xv[LSEG], yv[LSEG];
    if (flags[0]) {
        const __hip_bfloat16* xp = (const __hip_bfloat16*)x + xoff;
        #pragma unroll
        for (int l = 0; l < LSEG; ++l) xv[l] = __bfloat162float(xp[(size_t)l * HH]);
    } else {
        const float* xp = (const float*)x + xoff;
        #pragma unroll
        for (int l = 0; l < LSEG; ++l) xv[l] = xp[(size_t)l * HH];
    }
    float dh = Df[h];
    #pragma unroll
    for (int l = 0; l < LSEG; ++l) yv[l] = dh * xv[l];

    bool has = (seg > 0);
    int  segm1 = has ? (seg - 1) : 0;
    size_t sbase = (((size_t)(b*4 + hg) * NSEG + segm1) * NN) * 128 + lane;

    // software-pipelined n-loop loads (prefetch next n)
    float lre  = lam[0], lim = lam[1];
    float cbre = CBt[h], cbim = CBt[HH + h];
    float sre0 = has ? __bfloat162float(Abuf[sbase])      : 0.f;
    float sim0 = has ? __bfloat162float(Abuf[sbase + 64]) : 0.f;

    for (int n = 0; n < NN; ++n) {
        int n1 = (n + 1) & 63;
        float nlre  = lam[2*n1], nlim = lam[2*n1+1];
        float ncbre = CBt[(n1*2)*HH + h], ncbim = CBt[(n1*2+1)*HH + h];
        float nsre  = has ? __bfloat162float(Abuf[sbase + (size_t)n1*128])      : 0.f;
        float nsim  = has ? __bfloat162float(Abuf[sbase + (size_t)n1*128 + 64]) : 0.f;

        float sre = sre0, sim = sim0;
        #pragma unroll
        for (int l = 0; l < LSEG; ++l) {
            float t = fmaf(lre, sre, xv[l]);      // s_re' = lre*sre - lim*sim + x
            t = fmaf(-lim, sim, t);
            sim = fmaf(lre, sim, lim * sre);      // s_im' = lre*sim + lim*sre (old sre)
            sre = t;
            yv[l] = fmaf(cbre, sre, yv[l]);       // y += Re(CB * s)
            yv[l] = fmaf(-cbim, sim, yv[l]);
        }
        lre = nlre; lim = nlim; cbre = ncbre; cbim = ncbim; sre0 = nsre; sim0 = nsim;
    }

    float* yp = y + xoff;                          // OUTPUT IS FP32
    #pragma unroll
    for (int l = 0; l < LSEG; ++l) yp[(size_t)l * HH] = yv[l];
}

extern "C" void kernel_launch(void* const* d_in, const int* in_sizes, int n_in,
                              void* d_out, int out_size, void* d_ws, size_t ws_size,
                              hipStream_t stream)
{
    const void* x  = d_in[0];
    const void* nu = d_in[1];
    const void* th = d_in[2];
    const void* Br = d_in[3];
    const void* Bi = d_in[4];
    const void* Cr = d_in[5];
    const void* Ci = d_in[6];
    const void* D  = d_in[7];

    char* ws = (char*)d_ws;
    float* lam   = (float*)(ws);
    float* lam64 = (float*)(ws + 512);
    int*   flags = (int*)(ws + 1024);
    float* Df    = (float*)(ws + 1088);
    float* CBt   = (float*)(ws + 2112);
    __hip_bfloat16* Abuf = (__hip_bfloat16*)(ws + 135168);
    float* yout = (float*)d_out;

    k_sniff<<<dim3(1), dim3(64), 0, stream>>>(x, nu, th, Br, Bi, Cr, Ci, D, flags);
    k_setup<<<dim3(64), dim3(256), 0, stream>>>(nu, th, Br, Bi, Cr, Ci, D, flags,
                                                lam, lam64, Df, CBt);
    k_segsum<<<dim3(512), dim3(256), 0, stream>>>(x, lam, flags, Abuf);
    k_scan<<<dim3(256), dim3(256), 0, stream>>>(lam64, Abuf);
    k_out<<<dim3(512), dim3(256), 0, stream>>>(x, lam, Df, CBt, flags, Abuf, yout);
}

// Round 4
// 274.101 us; speedup vs baseline: 1.0090x; 1.0090x over previous
//
#include <hip/hip_runtime.h>
#include <hip/hip_bf16.h>

#define BB   4
#define LL   8192
#define HH   256
#define NN   64
#define NSEG 128
#define LSEG 64

// ws layout (bytes):
//       0 : lam[2*NN]      f32  (512)    per-n lambda (re,im)
//     512 : lam64[2*NN]    f32  (512)    lambda^64
//    1024 : flags[8]       i32  (32)     per-input dtype: 1=bf16, 0=fp32
//    1088 : Df[HH]         f32  (1024)
//    2112 : CBt[NN*2*HH]   f32  (131072) [n][re/im][h]
//  135168 : Abuf           bf16 (33554432) [b][hg][seg][n][re/im][64 h-lane]
// total 33,689,600 B (~32.1 MiB)
//
// DTYPE MODEL (validated R0-R3): output fp32; inputs mixed, resolved by k_sniff.
// R4: __launch_bounds__(256,2) so xv[64]/yv[64] stay in VGPRs (R3 had
// VGPR_Count=72 => compiler was re-loading x from cache every n-iteration);
// k_segsum n-loop split across 2 waves (independent work, disjoint writes).

__device__ __forceinline__ float ldF(const void* p, size_t i, int isbf) {
    return isbf ? __bfloat162float(((const __hip_bfloat16*)p)[i])
                : ((const float*)p)[i];
}

__global__ void k_sniff(const void* p0, const void* p1, const void* p2,
                        const void* p3, const void* p4, const void* p5,
                        const void* p6, const void* p7, int* flags)
{
    int t = threadIdx.x;
    if (t < 8) {
        const void* ps[8] = {p0, p1, p2, p3, p4, p5, p6, p7};
        const unsigned int* d = (const unsigned int*)ps[t];
        int nbf = 0, nrand = 0;
        for (int i = 0; i < 32; ++i) {
            unsigned int lo = d[i] & 0xFFFFu;
            unsigned int e  = (lo >> 7) & 0xFFu;
            if (lo == 0u) { /* neutral */ }
            else if (e >= 90u && e <= 140u) nbf++;
            else nrand++;
        }
        flags[t] = (nrand == 0 && nbf >= 8) ? 1 : 0;
    }
}

__global__ __launch_bounds__(256) void k_setup(
    const void* nu_log, const void* theta_log,
    const void* B_re, const void* B_im,
    const void* C_re, const void* C_im,
    const void* D, const int* __restrict__ flags,
    float* lam, float* lam64, float* Df, float* CBt)
{
    int t = blockIdx.x * 256 + threadIdx.x;
    if (t < NN) {
        float nu = expf(ldF(nu_log, t, flags[1]));
        float th = expf(ldF(theta_log, t, flags[2]));
        float a  = expf(-nu);
        lam[2*t]   = a * cosf(th);
        lam[2*t+1] = a * sinf(th);
        float a64 = expf(-64.0f * nu);
        float ph  = 64.0f * th;
        lam64[2*t]   = a64 * cosf(ph);
        lam64[2*t+1] = a64 * sinf(ph);
    }
    if (t < HH) Df[t] = ldF(D, t, flags[7]);
    if (t < HH * NN) {
        int h = t >> 6, n = t & 63;
        float bre = ldF(B_re, h*NN+n, flags[3]);
        float bim = ldF(B_im, h*NN+n, flags[4]);
        float cre = ldF(C_re, h*NN+n, flags[5]);
        float cim = ldF(C_im, h*NN+n, flags[6]);
        CBt[(n*2+0)*HH + h] = cre*bre - cim*bim;
        CBt[(n*2+1)*HH + h] = cre*bim + cim*bre;
    }
}

// Phase A: segment-local weighted sums A[n] = sum_l lambda^(63-l) x_l
// R4: n-range split across wave pairs (bit 0 of wave id); 4096 waves total.
__global__ __launch_bounds__(256, 2) void k_segsum(
    const void* __restrict__ x, const float* __restrict__ lam,
    const int* __restrict__ flags, __hip_bfloat16* __restrict__ Abuf)
{
    int w    = blockIdx.x * 4 + (threadIdx.x >> 6);   // 0..4095
    int lane = threadIdx.x & 63;
    int half = w & 1;
    int seg  = (w >> 1) & (NSEG - 1);
    int hg   = (w >> 8) & 3;
    int b    = w >> 10;

    size_t xoff = (size_t)(b*LL + seg*LSEG) * HH + hg*64 + lane;
    float xv[LSEG];
    if (flags[0]) {
        const __hip_bfloat16* xp = (const __hip_bfloat16*)x + xoff;
        #pragma unroll
        for (int l = 0; l < LSEG; ++l) xv[l] = __bfloat162float(xp[(size_t)l * HH]);
    } else {
        const float* xp = (const float*)x + xoff;
        #pragma unroll
        for (int l = 0; l < LSEG; ++l) xv[l] = xp[(size_t)l * HH];
    }

    size_t abase = (((size_t)(b*4 + hg) * NSEG + seg) * NN) * 128 + lane;
    int n0 = half * 32;
    for (int n = n0; n < n0 + 32; ++n) {
        float lre = lam[2*n], lim = lam[2*n+1];
        float are = 0.f, aim = 0.f, pre = 1.f, pim = 0.f;
        #pragma unroll
        for (int i = 0; i < LSEG; ++i) {
            float xl = xv[LSEG - 1 - i];
            are = fmaf(pre, xl, are);
            aim = fmaf(pim, xl, aim);
            float t = fmaf(pre, lre, -(pim * lim));
            pim = fmaf(pre, lim, pim * lre);
            pre = t;
        }
        Abuf[abase + (size_t)n*128]      = __float2bfloat16(are);
        Abuf[abase + (size_t)n*128 + 64] = __float2bfloat16(aim);
    }
}

// Phase B: in-place scan across segments: S_end[s] = lam^64 * S_end[s-1] + A[s]
__global__ __launch_bounds__(256) void k_scan(
    const float* __restrict__ lam64, __hip_bfloat16* __restrict__ Abuf)
{
    int w    = blockIdx.x * 4 + (threadIdx.x >> 6);
    int lane = threadIdx.x & 63;
    int n    = w & 63;
    int hg   = (w >> 6) & 3;
    int b    = w >> 8;

    float lre = lam64[2*n], lim = lam64[2*n+1];
    float sre = 0.f, sim = 0.f;
    size_t base0 = (((size_t)(b*4 + hg) * NSEG) * NN + n) * 128 + lane;
    for (int s = 0; s < NSEG; ++s) {
        size_t base = base0 + (size_t)s * NN * 128;
        float are = __bfloat162float(Abuf[base]);
        float aim = __bfloat162float(Abuf[base + 64]);
        float t = fmaf(lre, sre, fmaf(-lim, sim, are));
        sim = fmaf(lre, sim, fmaf(lim, sre, aim));
        sre = t;
        Abuf[base]      = __float2bfloat16(sre);
        Abuf[base + 64] = __float2bfloat16(sim);
    }
}

// Phase C: re-run recurrence per segment seeded with S_end[seg-1], emit y (fp32)
__global__ __launch_bounds__(256, 2) void k_out(
    const void* __restrict__ x, const float* __restrict__ lam,
    const float* __restrict__ Df, const float* __restrict__ CBt,
    const int* __restrict__ flags,
    const __hip_bfloat16* __restrict__ Abuf, float* __restrict__ y)
{
    int w    = blockIdx.x * 4 + (threadIdx.x >> 6);
    int lane = threadIdx.x & 63;
    int seg  = w & (NSEG - 1);
    int hg   = (w >> 7) & 3;
    int b    = w >> 9;
    int h    = hg*64 + lane;

    size_t xoff = (size_t)(b*LL + seg*LSEG) * HH + h;
    float xv[LSEG], yv[LSEG];
    if (flags[0]) {
        const __hip_bfloat16* xp = (const __hip_bfloat16*)x + xoff;
        #pragma unroll
        for (int l = 0; l < LSEG; ++l) xv[l] = __bfloat162float(xp[(size_t)l * HH]);
    } else {
        const float* xp = (const float*)x + xoff;
        #pragma unroll
        for (int l = 0; l < LSEG; ++l) xv[l] = xp[(size_t)l * HH];
    }
    float dh = Df[h];
    #pragma unroll
    for (int l = 0; l < LSEG; ++l) yv[l] = dh * xv[l];

    bool has = (seg > 0);
    int  segm1 = has ? (seg - 1) : 0;
    size_t sbase = (((size_t)(b*4 + hg) * NSEG + segm1) * NN) * 128 + lane;

    // software-pipelined n-loop loads (prefetch next n)
    float lre  = lam[0], lim = lam[1];
    float cbre = CBt[h], cbim = CBt[HH + h];
    float sre0 = has ? __bfloat162float(Abuf[sbase])      : 0.f;
    float sim0 = has ? __bfloat162float(Abuf[sbase + 64]) : 0.f;

    for (int n = 0; n < NN; ++n) {
        int n1 = (n + 1) & 63;
        float nlre  = lam[2*n1], nlim = lam[2*n1+1];
        float ncbre = CBt[(n1*2)*HH + h], ncbim = CBt[(n1*2+1)*HH + h];
        float nsre  = has ? __bfloat162float(Abuf[sbase + (size_t)n1*128])      : 0.f;
        float nsim  = has ? __bfloat162float(Abuf[sbase + (size_t)n1*128 + 64]) : 0.f;

        float sre = sre0, sim = sim0;
        #pragma unroll
        for (int l = 0; l < LSEG; ++l) {
            float t = fmaf(lre, sre, xv[l]);      // s_re' = lre*sre - lim*sim + x
            t = fmaf(-lim, sim, t);
            sim = fmaf(lre, sim, lim * sre);      // s_im' = lre*sim + lim*sre (old sre)
            sre = t;
            yv[l] = fmaf(cbre, sre, yv[l]);       // y += Re(CB * s)
            yv[l] = fmaf(-cbim, sim, yv[l]);
        }
        lre = nlre; lim = nlim; cbre = ncbre; cbim = ncbim; sre0 = nsre; sim0 = nsim;
    }

    float* yp = y + xoff;                          // OUTPUT IS FP32
    #pragma unroll
    for (int l = 0; l < LSEG; ++l) yp[(size_t)l * HH] = yv[l];
}

extern "C" void kernel_launch(void* const* d_in, const int* in_sizes, int n_in,
                              void* d_out, int out_size, void* d_ws, size_t ws_size,
                              hipStream_t stream)
{
    const void* x  = d_in[0];
    const void* nu = d_in[1];
    const void* th = d_in[2];
    const void* Br = d_in[3];
    const void* Bi = d_in[4];
    const void* Cr = d_in[5];
    const void* Ci = d_in[6];
    const void* D  = d_in[7];

    char* ws = (char*)d_ws;
    float* lam   = (float*)(ws);
    float* lam64 = (float*)(ws + 512);
    int*   flags = (int*)(ws + 1024);
    float* Df    = (float*)(ws + 1088);
    float* CBt   = (float*)(ws + 2112);
    __hip_bfloat16* Abuf = (__hip_bfloat16*)(ws + 135168);
    float* yout = (float*)d_out;

    k_sniff<<<dim3(1), dim3(64), 0, stream>>>(x, nu, th, Br, Bi, Cr, Ci, D, flags);
    k_setup<<<dim3(64), dim3(256), 0, stream>>>(nu, th, Br, Bi, Cr, Ci, D, flags,
                                                lam, lam64, Df, CBt);
    k_segsum<<<dim3(1024), dim3(256), 0, stream>>>(x, lam, flags, Abuf);
    k_scan<<<dim3(256), dim3(256), 0, stream>>>(lam64, Abuf);
    k_out<<<dim3(512), dim3(256), 0, stream>>>(x, lam, Df, CBt, flags, Abuf, yout);
}

// Round 5
// 262.039 us; speedup vs baseline: 1.0554x; 1.0460x over previous
//
#include <hip/hip_runtime.h>
#include <hip/hip_bf16.h>

#define BB   4
#define LL   8192
#define HH   256
#define NN   64
#define NSEG 128
#define LSEG 64

// ws layout (bytes):
//       0 : lam[2*NN]      f32  (512)    per-n lambda (re,im)
//     512 : lam64[2*NN]    f32  (512)    lambda^64
//    1024 : flags[8]       i32  (32)     per-input dtype: 1=bf16, 0=fp32
//    1088 : Df[HH]         f32  (1024)
//    2112 : CBt[NN*2*HH]   f32  (131072) [n][re/im][h]
//  135168 : Abuf           bf16 (33554432) [b][hg][seg][n][re/im][64 h-lane]
//
// DTYPE MODEL (validated R0-R3): output fp32; inputs mixed, resolved by k_sniff.
// R5: R3/R4's k_out had VGPR=72 (compiler strip-mined xv[64]/yv[64], re-loading
// x from L1 anyway). Embrace it: no xv arrays — load x per (n,l) from L1
// (8 KB/wave working set). Only yv[64] lives in registers (k_out). segsum uses
// the 4-VALU recurrence form a <- lam*a + x instead of the 6-VALU power form.

__device__ __forceinline__ float ldF(const void* p, size_t i, int isbf) {
    return isbf ? __bfloat162float(((const __hip_bfloat16*)p)[i])
                : ((const float*)p)[i];
}

__global__ void k_sniff(const void* p0, const void* p1, const void* p2,
                        const void* p3, const void* p4, const void* p5,
                        const void* p6, const void* p7, int* flags)
{
    int t = threadIdx.x;
    if (t < 8) {
        const void* ps[8] = {p0, p1, p2, p3, p4, p5, p6, p7};
        const unsigned int* d = (const unsigned int*)ps[t];
        int nbf = 0, nrand = 0;
        for (int i = 0; i < 32; ++i) {
            unsigned int lo = d[i] & 0xFFFFu;
            unsigned int e  = (lo >> 7) & 0xFFu;
            if (lo == 0u) { /* neutral */ }
            else if (e >= 90u && e <= 140u) nbf++;
            else nrand++;
        }
        flags[t] = (nrand == 0 && nbf >= 8) ? 1 : 0;
    }
}

__global__ __launch_bounds__(256) void k_setup(
    const void* nu_log, const void* theta_log,
    const void* B_re, const void* B_im,
    const void* C_re, const void* C_im,
    const void* D, const int* __restrict__ flags,
    float* lam, float* lam64, float* Df, float* CBt)
{
    int t = blockIdx.x * 256 + threadIdx.x;
    if (t < NN) {
        float nu = expf(ldF(nu_log, t, flags[1]));
        float th = expf(ldF(theta_log, t, flags[2]));
        float a  = expf(-nu);
        lam[2*t]   = a * cosf(th);
        lam[2*t+1] = a * sinf(th);
        float a64 = expf(-64.0f * nu);
        float ph  = 64.0f * th;
        lam64[2*t]   = a64 * cosf(ph);
        lam64[2*t+1] = a64 * sinf(ph);
    }
    if (t < HH) Df[t] = ldF(D, t, flags[7]);
    if (t < HH * NN) {
        int h = t >> 6, n = t & 63;
        float bre = ldF(B_re, h*NN+n, flags[3]);
        float bim = ldF(B_im, h*NN+n, flags[4]);
        float cre = ldF(C_re, h*NN+n, flags[5]);
        float cim = ldF(C_im, h*NN+n, flags[6]);
        CBt[(n*2+0)*HH + h] = cre*bre - cim*bim;
        CBt[(n*2+1)*HH + h] = cre*bim + cim*bre;
    }
}

// ---------- Phase A: A[n] = sum_l lam^(63-l) x_l  (recurrence form) ----------
template<bool ISBF>
__device__ __forceinline__ void segsum_body(
    const void* __restrict__ x, size_t xoff, const float* __restrict__ lam,
    __hip_bfloat16* __restrict__ Abuf, size_t abase, int n0)
{
    for (int n = n0; n < n0 + 32; ++n) {
        float lre = lam[2*n], lim = lam[2*n+1];
        float are = 0.f, aim = 0.f;
        #pragma unroll
        for (int l = 0; l < LSEG; ++l) {
            float xl;
            if (ISBF) xl = __bfloat162float(((const __hip_bfloat16*)x)[xoff + (size_t)l*HH]);
            else      xl = ((const float*)x)[xoff + (size_t)l*HH];
            float t0 = lim * are;
            are = fmaf(lre, are, xl);
            are = fmaf(-lim, aim, are);
            aim = fmaf(lre, aim, t0);
        }
        Abuf[abase + (size_t)n*128]      = __float2bfloat16(are);
        Abuf[abase + (size_t)n*128 + 64] = __float2bfloat16(aim);
    }
}

__global__ __launch_bounds__(256) void k_segsum(
    const void* __restrict__ x, const float* __restrict__ lam,
    const int* __restrict__ flags, __hip_bfloat16* __restrict__ Abuf)
{
    int w    = blockIdx.x * 4 + (threadIdx.x >> 6);   // 0..4095
    int lane = threadIdx.x & 63;
    int half = w & 1;
    int seg  = (w >> 1) & (NSEG - 1);
    int hg   = (w >> 8) & 3;
    int b    = w >> 10;

    size_t xoff  = (size_t)(b*LL + seg*LSEG) * HH + hg*64 + lane;
    size_t abase = (((size_t)(b*4 + hg) * NSEG + seg) * NN) * 128 + lane;
    int n0 = half * 32;

    if (flags[0]) segsum_body<true >(x, xoff, lam, Abuf, abase, n0);
    else          segsum_body<false>(x, xoff, lam, Abuf, abase, n0);
}

// ---------- Phase B: scan across segments ----------
__global__ __launch_bounds__(256) void k_scan(
    const float* __restrict__ lam64, __hip_bfloat16* __restrict__ Abuf)
{
    int w    = blockIdx.x * 4 + (threadIdx.x >> 6);
    int lane = threadIdx.x & 63;
    int n    = w & 63;
    int hg   = (w >> 6) & 3;
    int b    = w >> 8;

    float lre = lam64[2*n], lim = lam64[2*n+1];
    float sre = 0.f, sim = 0.f;
    size_t base0 = (((size_t)(b*4 + hg) * NSEG) * NN + n) * 128 + lane;
    #pragma unroll 4
    for (int s = 0; s < NSEG; ++s) {
        size_t base = base0 + (size_t)s * NN * 128;
        float are = __bfloat162float(Abuf[base]);
        float aim = __bfloat162float(Abuf[base + 64]);
        float t = fmaf(lre, sre, fmaf(-lim, sim, are));
        sim = fmaf(lre, sim, fmaf(lim, sre, aim));
        sre = t;
        Abuf[base]      = __float2bfloat16(sre);
        Abuf[base + 64] = __float2bfloat16(sim);
    }
}

// ---------- Phase C: recurrence per segment seeded with S_end[seg-1] ----------
template<bool ISBF>
__device__ __forceinline__ void out_body(
    const void* __restrict__ x, size_t xoff, const float* __restrict__ lam,
    const float* __restrict__ CBt, int h, float dh,
    bool has, const __hip_bfloat16* __restrict__ seedp,
    float* __restrict__ y)
{
    float yv[LSEG];
    #pragma unroll
    for (int l = 0; l < LSEG; ++l) {
        float xl;
        if (ISBF) xl = __bfloat162float(((const __hip_bfloat16*)x)[xoff + (size_t)l*HH]);
        else      xl = ((const float*)x)[xoff + (size_t)l*HH];
        yv[l] = dh * xl;
    }

    for (int n = 0; n < NN; ++n) {
        float lre  = lam[2*n], lim = lam[2*n+1];
        float cbre = CBt[(2*n)*HH + h], cbim = CBt[(2*n+1)*HH + h];
        float sre  = has ? __bfloat162float(seedp[(size_t)n*128])      : 0.f;
        float sim  = has ? __bfloat162float(seedp[(size_t)n*128 + 64]) : 0.f;
        #pragma unroll
        for (int l = 0; l < LSEG; ++l) {
            float xl;
            if (ISBF) xl = __bfloat162float(((const __hip_bfloat16*)x)[xoff + (size_t)l*HH]);
            else      xl = ((const float*)x)[xoff + (size_t)l*HH];
            float t0 = lim * sre;
            sre = fmaf(lre, sre, xl);
            sre = fmaf(-lim, sim, sre);
            sim = fmaf(lre, sim, t0);
            yv[l] = fmaf(cbre, sre, yv[l]);
            yv[l] = fmaf(-cbim, sim, yv[l]);
        }
    }

    #pragma unroll
    for (int l = 0; l < LSEG; ++l) y[xoff + (size_t)l*HH] = yv[l];
}

__global__ __launch_bounds__(256) void k_out(
    const void* __restrict__ x, const float* __restrict__ lam,
    const float* __restrict__ Df, const float* __restrict__ CBt,
    const int* __restrict__ flags,
    const __hip_bfloat16* __restrict__ Abuf, float* __restrict__ y)
{
    int w    = blockIdx.x * 4 + (threadIdx.x >> 6);    // 0..2047
    int lane = threadIdx.x & 63;
    int seg  = w & (NSEG - 1);
    int hg   = (w >> 7) & 3;
    int b    = w >> 9;
    int h    = hg*64 + lane;

    size_t xoff = (size_t)(b*LL + seg*LSEG) * HH + h;
    float dh = Df[h];

    bool has  = (seg > 0);
    int segm1 = has ? (seg - 1) : 0;
    const __hip_bfloat16* seedp =
        Abuf + (((size_t)(b*4 + hg) * NSEG + segm1) * NN) * 128 + lane;

    if (flags[0]) out_body<true >(x, xoff, lam, CBt, h, dh, has, seedp, y);
    else          out_body<false>(x, xoff, lam, CBt, h, dh, has, seedp, y);
}

extern "C" void kernel_launch(void* const* d_in, const int* in_sizes, int n_in,
                              void* d_out, int out_size, void* d_ws, size_t ws_size,
                              hipStream_t stream)
{
    const void* x  = d_in[0];
    const void* nu = d_in[1];
    const void* th = d_in[2];
    const void* Br = d_in[3];
    const void* Bi = d_in[4];
    const void* Cr = d_in[5];
    const void* Ci = d_in[6];
    const void* D  = d_in[7];

    char* ws = (char*)d_ws;
    float* lam   = (float*)(ws);
    float* lam64 = (float*)(ws + 512);
    int*   flags = (int*)(ws + 1024);
    float* Df    = (float*)(ws + 1088);
    float* CBt   = (float*)(ws + 2112);
    __hip_bfloat16* Abuf = (__hip_bfloat16*)(ws + 135168);
    float* yout = (float*)d_out;

    k_sniff<<<dim3(1), dim3(64), 0, stream>>>(x, nu, th, Br, Bi, Cr, Ci, D, flags);
    k_setup<<<dim3(64), dim3(256), 0, stream>>>(nu, th, Br, Bi, Cr, Ci, D, flags,
                                                lam, lam64, Df, CBt);
    k_segsum<<<dim3(1024), dim3(256), 0, stream>>>(x, lam, flags, Abuf);
    k_scan<<<dim3(256), dim3(256), 0, stream>>>(lam64, Abuf);
    k_out<<<dim3(512), dim3(256), 0, stream>>>(x, lam, Df, CBt, flags, Abuf, yout);
}